// Round 1
// baseline (116.737 us; speedup 1.0000x reference)
//
#include <hip/hip_runtime.h>

#define TAU 3.0f
#define FIX 0.2f
#define NPED 1024              // N per batch (reference setup)
#define PEDS_PER_BLOCK 256
#define BLOCK 512
#define GROUPS (BLOCK / 8)                      // 64 peds per pass
#define PASSES (PEDS_PER_BLOCK / GROUPS)        // 4

typedef int   v4i __attribute__((ext_vector_type(4)));
typedef float v4f __attribute__((ext_vector_type(4)));

// Width-8 sum-reduce step on the VALU via DPP row_shl:N (lane i += lane i+N).
// bound_ctrl=true zeroes out-of-row reads; cross-subgroup garbage only lands
// in lanes >= sub 1 which are never consumed after the final step.
template <int CTRL>
__device__ __forceinline__ float dpp_shl_add(float x) {
    union { float f; int i; } s, r;
    s.f = x;
    r.i = __builtin_amdgcn_update_dpp(0, s.i, CTRL, 0xF, 0xF, true);
    return x + r.f;
}

// Layout: 8 lanes per pedestrian (sub = tid&7), each lane handles 4 neighbors.
// LDS holds the batch's pos+vel packed as float4 (ONE ds_read_b128 gather per
// neighbor instead of two ds_read_b64: fewer lgkmcnt events, ~20% less LDS
// pipe under uniform-random conflict load).
__global__ __launch_bounds__(BLOCK, 8) void rvo_kernel(
    const float* __restrict__ p_cur,     // (B,N,2)
    const float* __restrict__ v_cur,     // (B,N,2)
    const float* __restrict__ v_desire,  // (B,N,2)
    const int*   __restrict__ near_idx,  // (B,N,32)
    const float* __restrict__ mask_arr,  // (B,N,32)
    const int*   __restrict__ cth,       // scalar
    float*       __restrict__ out,       // (B,N,2)
    int N)
{
    __shared__ float4 tpv[NPED];         // (px,py,vx,vy) per ped, 16 KB

    const int tid    = threadIdx.x;
    const int bpb    = N / PEDS_PER_BLOCK;          // blocks per batch = 4
    const int batch  = blockIdx.x / bpb;
    const int pbase  = (blockIdx.x % bpb) * PEDS_PER_BLOCK;

    // ---- stage packed pos/vel table: coalesced float2 reads, b128 LDS writes
    const float2* pb2 = (const float2*)(p_cur) + (size_t)batch * N;
    const float2* vb2 = (const float2*)(v_cur) + (size_t)batch * N;
    #pragma unroll
    for (int n = tid; n < NPED; n += BLOCK) {
        const float2 p = pb2[n];
        const float2 v = vb2[n];
        tpv[n] = make_float4(p.x, p.y, v.x, v.y);
    }
    __syncthreads();

    const float thr2 = (float)cth[0] * (float)cth[0];

    const int sub  = tid & 7;        // which 4-neighbor chunk (k = sub*4..sub*4+3)
    const int pgrp = tid >> 3;       // 0..63: pedestrian within pass

    const v4i*    idxv = (const v4i*)near_idx;
    const v4f*    mskv = (const v4f*)mask_arr;
    const float2* vdv  = (const float2*)v_desire;

    size_t pair = (size_t)batch * N + (pbase + pgrp);

    // ---- software pipeline: pass-0 streaming loads issued before the loop;
    //      each pass prefetches pass+1 so HBM latency hides under compute.
    //      Nontemporal: idx/mask are read-once 64 MB — keep them out of L2 so
    //      the hot 6 MB p/v/vd tables stay resident for other blocks.
    v4i    i4 = __builtin_nontemporal_load(&idxv[pair * 8 + sub]);
    v4f    m4 = __builtin_nontemporal_load(&mskv[pair * 8 + sub]);
    float2 vd = vdv[pair];

    #pragma unroll
    for (int pass = 0; pass < PASSES; ++pass) {
        v4i ni4; v4f nm4; float2 nvd;
        if (pass + 1 < PASSES) {
            const size_t np = pair + GROUPS;
            ni4 = __builtin_nontemporal_load(&idxv[np * 8 + sub]);
            nm4 = __builtin_nontemporal_load(&mskv[np * 8 + sub]);
            nvd = vdv[np];
        } else {            // dead on last pass (full unroll) — DCE'd
            ni4 = i4; nm4 = m4; nvd = vd;
        }

        const int ped = pbase + pass * GROUPS + pgrp;
        const float4 self = tpv[ped];              // 8-lane broadcast read
        const float px = self.x, py = self.y;
        const float vdx = vd.x, vdy = vd.y;

        const int   idxs[4] = {i4.x, i4.y, i4.z, i4.w};
        const float ms[4]   = {m4.x, m4.y, m4.z, m4.w};

        float nx = 0.0f, ny = 0.0f;
        #pragma unroll
        for (int j = 0; j < 4; ++j) {
            const float4 nb = tpv[idxs[j]];        // single ds_read_b128 gather
            const float m = ms[j];
            // rel = self - nb*m, fused: fma(-m, nb, self)
            const float rpx = fmaf(-m, nb.x, px);
            const float rpy = fmaf(-m, nb.y, py);
            const float rvx = fmaf(-m, nb.z, vdx);
            const float rvy = fmaf(-m, nb.w, vdy);

            const float dpv = fmaf(rpx, rvx, rpy * rvy);
            const float dvv = fmaf(rvx, rvx, fmaf(rvy, rvy, 2e-6f)); // eps folded
            float t = dpv * __builtin_amdgcn_rcpf(dvv);
            t = fminf(fmaxf(t, 0.0f), TAU);        // inputs finite -> no NaN

            const float cx = fmaf(t, rvx, rpx);
            const float cy = fmaf(t, rvy, rpy);
            const float md2 = fmaf(cx, cx, cy * cy);   // compare squared dist

            const float s = fmaf(rpx, rpx, rpy * rpy);
            // s>0 guard: self-neighbor (s==0, m==1) contributes exactly 0
            // (ref: 0/(0+1e-6) == 0). rsq rel-err ~1e-7 vs 9.25e-2 threshold.
            const float sel0 = (s > 0.0f) ? __builtin_amdgcn_rsqf(s) : 0.0f;
            const float w    = (md2 < thr2) ? m : 0.0f;  // m in {0,1}
            const float sel  = sel0 * w;
            nx = fmaf(-rpy, sel, nx);
            ny = fmaf( rpx, sel, ny);
        }

        // width-8 reduction on the VALU (DPP row_shl) — no ds_bpermute,
        // no lgkmcnt round-trips, frees the LDS pipe for the gathers.
        nx = dpp_shl_add<0x104>(nx);   // += lane+4
        nx = dpp_shl_add<0x102>(nx);   // += lane+2
        nx = dpp_shl_add<0x101>(nx);   // += lane+1
        ny = dpp_shl_add<0x104>(ny);
        ny = dpp_shl_add<0x102>(ny);
        ny = dpp_shl_add<0x101>(ny);

        if (sub == 0) {
            ((float2*)out)[pair] = make_float2(fmaf(nx, FIX, vdx),
                                               fmaf(ny, FIX, vdy));
        }

        pair += GROUPS;
        i4 = ni4; m4 = nm4; vd = nvd;
    }
}

extern "C" void kernel_launch(void* const* d_in, const int* in_sizes, int n_in,
                              void* d_out, int out_size, void* d_ws, size_t ws_size,
                              hipStream_t stream) {
    const float* p_cur    = (const float*)d_in[0];
    const float* v_cur    = (const float*)d_in[1];
    const float* v_desire = (const float*)d_in[2];
    const int*   near_idx = (const int*)d_in[3];
    const float* mask_arr = (const float*)d_in[4];
    const int*   cth      = (const int*)d_in[5];
    float*       out      = (float*)d_out;

    const int N  = NPED;
    const int BN = in_sizes[0] / 2;          // B*N pedestrians
    dim3 block(BLOCK);
    dim3 grid(BN / PEDS_PER_BLOCK);          // 1024 blocks for B=256
    rvo_kernel<<<grid, block, 0, stream>>>(p_cur, v_cur, v_desire, near_idx,
                                           mask_arr, cth, out, N);
}

// Round 2
// 105.278 us; speedup vs baseline: 1.1088x; 1.1088x over previous
//
#include <hip/hip_runtime.h>

#define TAU 3.0f
#define FIX 0.2f
#define NPED 1024              // N per batch (reference setup)
#define PEDS_PER_BLOCK 256
#define BLOCK 512
#define GROUPS (BLOCK / 8)                      // 64 peds per pass
#define PASSES (PEDS_PER_BLOCK / GROUPS)        // 4

// Width-8 sum-reduce step on the VALU via DPP row_shl:N (lane i += lane i+N).
// bound_ctrl=true zeroes out-of-row reads. Chain verified: for sub=0,
// r1(k)=x(k)+x(k+4) k=0..3 (in-subgroup), r2(0)=r1(0)+r1(2), r2(1)=r1(1)+r1(3),
// r3(0)=r2(0)+r2(1) = full 8-lane sum. Cross-subgroup garbage only lands in
// lanes sub>=4 / sub>=2 / sub>=1 which are never consumed downstream.
// (Passed harness refcheck in round 1, absmax identical to shuffle version.)
template <int CTRL>
__device__ __forceinline__ float dpp_shl_add(float x) {
    union { float f; int i; } s, r;
    s.f = x;
    r.i = __builtin_amdgcn_update_dpp(0, s.i, CTRL, 0xF, 0xF, true);
    return x + r.f;
}

// Layout: 8 lanes per pedestrian (sub = tid&7), each lane handles 4 neighbors.
// LDS holds the batch's pos/vel tables SPLIT as float2 (bank-conflict relief:
// float4 gathers have conflict class idx%8; float2 gathers idx%16 — A/B'd).
__global__ __launch_bounds__(BLOCK) void rvo_kernel(
    const float* __restrict__ p_cur,     // (B,N,2)
    const float* __restrict__ v_cur,     // (B,N,2)
    const float* __restrict__ v_desire,  // (B,N,2)
    const int*   __restrict__ near_idx,  // (B,N,32)
    const float* __restrict__ mask_arr,  // (B,N,32)
    const int*   __restrict__ cth,       // scalar
    float*       __restrict__ out,       // (B,N,2)
    int N)
{
    __shared__ float2 tpos[NPED];
    __shared__ float2 tvel[NPED];

    const int tid    = threadIdx.x;
    const int bpb    = N / PEDS_PER_BLOCK;          // blocks per batch = 4
    const int batch  = blockIdx.x / bpb;
    const int pbase  = (blockIdx.x % bpb) * PEDS_PER_BLOCK;

    // ---- stage pos/vel tables: coalesced float2 reads, stride-1 LDS writes ----
    const float2* pb2 = (const float2*)(p_cur) + (size_t)batch * N;
    const float2* vb2 = (const float2*)(v_cur) + (size_t)batch * N;
    #pragma unroll
    for (int n = tid; n < NPED; n += BLOCK) {
        tpos[n] = pb2[n];
        tvel[n] = vb2[n];
    }
    __syncthreads();

    const float thr2 = (float)cth[0] * (float)cth[0];

    const int sub  = tid & 7;        // which 4-neighbor chunk (k = sub*4..sub*4+3)
    const int pgrp = tid >> 3;       // 0..63: pedestrian within pass

    #pragma unroll
    for (int pass = 0; pass < PASSES; ++pass) {
        const int ped  = pbase + pass * GROUPS + pgrp;
        const size_t pair = (size_t)batch * N + ped;

        // broadcast per-ped scalars (8 lanes same address)
        const float2 self = tpos[ped];
        const float2 vd   = ((const float2*)v_desire)[pair];
        const float px = self.x, py = self.y;
        const float vdx = vd.x, vdy = vd.y;

        // coalesced vector loads: 32 idx/mask per ped = 8 int4/float4
        const int4   i4 = ((const int4*)near_idx)[pair * 8 + sub];
        const float4 m4 = ((const float4*)mask_arr)[pair * 8 + sub];
        const int   idxs[4] = {i4.x, i4.y, i4.z, i4.w};
        const float ms[4]   = {m4.x, m4.y, m4.z, m4.w};

        float nx = 0.0f, ny = 0.0f;
        #pragma unroll
        for (int j = 0; j < 4; ++j) {
            const float m = ms[j];
            // Masked neighbors (m==0, ~50% of lanes) contribute exactly 0:
            // redirect them to index 0 so all masked lanes hit ONE address ->
            // LDS broadcast (conflict-free). Random bank pressure now comes
            // from only the ~32 active lanes. Math unchanged: fmaf(-0,nb,self)
            // == self, and the weight w is 0 for these lanes anyway.
            const int gidx = (m != 0.0f) ? idxs[j] : 0;
            const float2 nbp = tpos[gidx];    // ds_read_b64 gather
            const float2 nbv = tvel[gidx];    // ds_read_b64 gather
            // rel = self - nb*m, fused: fma(-m, nb, self)
            const float rpx = fmaf(-m, nbp.x, px);
            const float rpy = fmaf(-m, nbp.y, py);
            const float rvx = fmaf(-m, nbv.x, vdx);
            const float rvy = fmaf(-m, nbv.y, vdy);

            const float dpv = fmaf(rpx, rvx, rpy * rvy);
            const float dvv = fmaf(rvx, rvx, fmaf(rvy, rvy, 2e-6f)); // eps folded
            float t = dpv * __builtin_amdgcn_rcpf(dvv);
            t = fminf(fmaxf(t, 0.0f), TAU);      // inputs finite -> no NaN

            const float cx = fmaf(t, rvx, rpx);
            const float cy = fmaf(t, rvy, rpy);
            const float md2 = fmaf(cx, cx, cy * cy);   // compare squared dist

            const float s = fmaf(rpx, rpx, rpy * rpy);
            // s>0 guard: self-neighbor (s==0, m==1) contributes exactly 0
            // (ref: 0/(0+1e-6) == 0). rsq rel-err ~1e-7 vs 9.25e-2 threshold.
            const float sel0 = (s > 0.0f) ? __builtin_amdgcn_rsqf(s) : 0.0f;
            const float w    = (md2 < thr2) ? m : 0.0f;  // m in {0,1}
            const float sel  = sel0 * w;
            nx = fmaf(-rpy, sel, nx);
            ny = fmaf( rpx, sel, ny);
        }

        // width-8 reduction on the VALU (DPP row_shl) — no ds_bpermute,
        // no serial lgkmcnt round-trips, frees the LDS pipe for the gathers.
        nx = dpp_shl_add<0x104>(nx);   // += lane+4
        nx = dpp_shl_add<0x102>(nx);   // += lane+2
        nx = dpp_shl_add<0x101>(nx);   // += lane+1
        ny = dpp_shl_add<0x104>(ny);
        ny = dpp_shl_add<0x102>(ny);
        ny = dpp_shl_add<0x101>(ny);

        if (sub == 0) {
            ((float2*)out)[pair] = make_float2(fmaf(nx, FIX, vdx),
                                               fmaf(ny, FIX, vdy));
        }
    }
}

extern "C" void kernel_launch(void* const* d_in, const int* in_sizes, int n_in,
                              void* d_out, int out_size, void* d_ws, size_t ws_size,
                              hipStream_t stream) {
    const float* p_cur    = (const float*)d_in[0];
    const float* v_cur    = (const float*)d_in[1];
    const float* v_desire = (const float*)d_in[2];
    const int*   near_idx = (const int*)d_in[3];
    const float* mask_arr = (const float*)d_in[4];
    const int*   cth      = (const int*)d_in[5];
    float*       out      = (float*)d_out;

    const int N  = NPED;
    const int BN = in_sizes[0] / 2;          // B*N pedestrians
    dim3 block(BLOCK);
    dim3 grid(BN / PEDS_PER_BLOCK);          // 1024 blocks for B=256
    rvo_kernel<<<grid, block, 0, stream>>>(p_cur, v_cur, v_desire, near_idx,
                                           mask_arr, cth, out, N);
}